// Round 1
// baseline (5751.603 us; speedup 1.0000x reference)
//
#include <hip/hip_runtime.h>
#include <hip/hip_bf16.h>
#include <cstdint>

typedef __attribute__((ext_vector_type(4))) float f32x4;
typedef __attribute__((ext_vector_type(8))) short s16x8;

#define BDIM 256

// ---------------------------------------------------------------------------
// Generic bf16 MFMA gemm: out[M,N] = act( A[M,K] @ W[N,K]^T + bias[N] )
// A is split into two row-major segments: A1 [M,K1] and A2 [M,K2] (concat on K).
// W is row-major [N, K1+K2] (exactly the torch weight layout => B-operand layout).
// blockIdx.z picks between two parameter sets (used to fuse gi+gh in one launch).
// ---------------------------------------------------------------------------
struct GemmP {
    const __hip_bfloat16* A1;
    const __hip_bfloat16* A2;
    const __hip_bfloat16* W;
    const float* bias;
    float* outF;
    __hip_bfloat16* outB;
};

template <int BM, int BN, int ACT, bool OUTB>
__global__ __launch_bounds__(BDIM) void gemm_k(GemmP p0, GemmP p1, int K1, int K2, int M, int N) {
    constexpr int LDT = 40;  // shorts per LDS row: 32 + 8 pad (80B stride -> ~2-way, free)
    __shared__ short lA[BM * LDT];
    __shared__ short lW[BN * LDT];
    const GemmP p = (blockIdx.z == 0) ? p0 : p1;
    const int K = K1 + K2;
    const int bm = blockIdx.x * BM;
    const int bn = blockIdx.y * BN;
    const int tid = threadIdx.x;
    const int lane = tid & 63;
    const int wid = tid >> 6;
    constexpr int WM = BM / 2, WN = BN / 2;   // 2x2 wave grid
    constexpr int TM = WM / 16, TN = WN / 16; // mfma tiles per wave
    const int wm = (wid >> 1) * WM;
    const int wn = (wid & 1) * WN;
    const int q = lane >> 4, l16 = lane & 15;

    f32x4 acc[TM][TN] = {};

    for (int k0 = 0; k0 < K; k0 += 32) {
        // stage A tile [BM x 32] (16B chunks; segment select is tile-uniform since 32 | K1)
        for (int c = tid; c < BM * 4; c += BDIM) {
            int row = c >> 2, kc = c & 3;
            int k = k0 + kc * 8;
            const __hip_bfloat16* src;
            if (k < K1) src = p.A1 + (size_t)(bm + row) * K1 + k;
            else        src = p.A2 + (size_t)(bm + row) * K2 + (k - K1);
            *(s16x8*)(lA + row * LDT + kc * 8) = *(const s16x8*)src;
        }
        // stage W tile [BN x 32]
        for (int c = tid; c < BN * 4; c += BDIM) {
            int row = c >> 2, kc = c & 3;
            int k = k0 + kc * 8;
            *(s16x8*)(lW + row * LDT + kc * 8) =
                *(const s16x8*)(p.W + (size_t)(bn + row) * K + k);
        }
        __syncthreads();

        s16x8 af[TM], wf[TN];
#pragma unroll
        for (int i = 0; i < TM; i++)
            af[i] = *(const s16x8*)(lA + (wm + i * 16 + l16) * LDT + q * 8);
#pragma unroll
        for (int j = 0; j < TN; j++)
            wf[j] = *(const s16x8*)(lW + (wn + j * 16 + l16) * LDT + q * 8);
#pragma unroll
        for (int i = 0; i < TM; i++)
#pragma unroll
            for (int j = 0; j < TN; j++)
                acc[i][j] = __builtin_amdgcn_mfma_f32_16x16x32_bf16(af[i], wf[j], acc[i][j], 0, 0, 0);
        __syncthreads();
    }

    // epilogue: D mapping col=lane&15, row=(lane>>4)*4+r
#pragma unroll
    for (int i = 0; i < TM; i++)
#pragma unroll
        for (int j = 0; j < TN; j++)
#pragma unroll
            for (int r = 0; r < 4; r++) {
                int row = bm + wm + i * 16 + q * 4 + r;
                int col = bn + wn + j * 16 + l16;
                float v = acc[i][j][r] + p.bias[col];
                if (ACT == 1) v = v > 0.0f ? v : expm1f(v);  // ELU
                if (OUTB) p.outB[(size_t)row * N + col] = __float2bfloat16(v);
                else      p.outF[(size_t)row * N + col] = v;
            }
}

// ---------------------------------------------------------------------------
// GRU pointwise: h = (1-z)*n + z*belief  (fp32; also emit bf16 copies)
// ---------------------------------------------------------------------------
__global__ __launch_bounds__(BDIM) void gru_pw(const float* __restrict__ gi, const float* __restrict__ gh,
                                               const float* __restrict__ bel, float* __restrict__ h_out,
                                               __hip_bfloat16* __restrict__ h_b,
                                               __hip_bfloat16* __restrict__ hs_bt) {
    int idx = blockIdx.x * BDIM + threadIdx.x;  // B*1024
    int b = idx >> 10, j = idx & 1023;
    size_t o = (size_t)b * 3072 + j;
    float r = gi[o] + gh[o];
    float z = gi[o + 1024] + gh[o + 1024];
    float ni = gi[o + 2048], nh = gh[o + 2048];
    r = 1.0f / (1.0f + expf(-r));
    z = 1.0f / (1.0f + expf(-z));
    float n = tanhf(ni + r * nh);
    float h = (1.0f - z) * n + z * bel[idx];
    h_out[idx] = h;
    __hip_bfloat16 hb = __float2bfloat16(h);
    h_b[idx] = hb;
    hs_bt[idx] = hb;
}

// ---------------------------------------------------------------------------
// Head pointwise: split [m|s_raw], s=softplus(s_raw)+0.1, state=m+s*eps.
// Optionally also prepares next-step s_b = bf16(state * nt_next) (posterior only).
// ---------------------------------------------------------------------------
__global__ __launch_bounds__(BDIM) void head_pw(const float* __restrict__ msq, const float* __restrict__ eps,
                                                float* __restrict__ o_st, float* __restrict__ o_mu,
                                                float* __restrict__ o_sd, int total,
                                                const float* __restrict__ nt_next,
                                                __hip_bfloat16* __restrict__ s_b) {
    int idx = blockIdx.x * BDIM + threadIdx.x;
    if (idx >= total) return;
    int b = idx >> 7, j = idx & 127;
    float m = msq[(size_t)b * 256 + j];
    float sraw = msq[(size_t)b * 256 + 128 + j];
    float s = (sraw > 20.0f ? sraw : log1pf(expf(sraw))) + 0.1f;
    float st = m + s * eps[idx];
    o_mu[idx] = m;
    o_sd[idx] = s;
    o_st[idx] = st;
    if (nt_next) s_b[idx] = __float2bfloat16(st * nt_next[b]);
}

// ---------------------------------------------------------------------------
// Init: s_b = bf16(prev_state * nt[0]), belief_b = bf16(prev_belief)
// ---------------------------------------------------------------------------
__global__ __launch_bounds__(BDIM) void init_k(const float* __restrict__ prev_state,
                                               const float* __restrict__ nt0,
                                               const float* __restrict__ prev_belief,
                                               __hip_bfloat16* __restrict__ s_b,
                                               __hip_bfloat16* __restrict__ bel_b) {
    int idx = blockIdx.x * BDIM + threadIdx.x;
    if (idx < 256 * 1024) bel_b[idx] = __float2bfloat16(prev_belief[idx]);
    if (idx < 256 * 128) {
        int b = idx >> 7;
        s_b[idx] = __float2bfloat16(prev_state[idx] * nt0[b]);
    }
}

// ---------------------------------------------------------------------------
// fp32 -> bf16 conversion of 9 arrays in one launch (float4-vectorized)
// ---------------------------------------------------------------------------
struct ConvP {
    const float* src[9];
    __hip_bfloat16* dst[9];
    int n4[9];
};

__global__ __launch_bounds__(BDIM) void conv_k(ConvP cp) {
    int stride = gridDim.x * BDIM;
    int g = blockIdx.x * BDIM + threadIdx.x;
    for (int s = 0; s < 9; s++) {
        const float4* src = (const float4*)cp.src[s];
        unsigned short* dst = (unsigned short*)cp.dst[s];
        int n4 = cp.n4[s];
        for (int i = g; i < n4; i += stride) {
            float4 v = src[i];
            __hip_bfloat16 h0 = __float2bfloat16(v.x), h1 = __float2bfloat16(v.y);
            __hip_bfloat16 h2 = __float2bfloat16(v.z), h3 = __float2bfloat16(v.w);
            ushort4 o;
            o.x = *(unsigned short*)&h0;
            o.y = *(unsigned short*)&h1;
            o.z = *(unsigned short*)&h2;
            o.w = *(unsigned short*)&h3;
            *(ushort4*)(dst + (size_t)4 * i) = o;
        }
    }
}

// ---------------------------------------------------------------------------
extern "C" void kernel_launch(void* const* d_in, const int* in_sizes, int n_in,
                              void* d_out, int out_size, void* d_ws, size_t ws_size,
                              hipStream_t stream) {
    constexpr int B = 256, T = 50;
    constexpr int BELIEF = 1024, STATE = 128, ACTION = 32, HIDDEN = 1024, EMBED = 1024;

    const float* prev_state  = (const float*)d_in[0];
    const float* actions     = (const float*)d_in[1];
    const float* prev_belief = (const float*)d_in[2];
    const float* observ      = (const float*)d_in[3];
    const float* nonterm     = (const float*)d_in[4];
    const float* eps_p       = (const float*)d_in[5];
    const float* eps_q       = (const float*)d_in[6];
    const float* W_sa  = (const float*)d_in[7];
    const float* b_sa  = (const float*)d_in[8];
    const float* W_ih  = (const float*)d_in[9];
    const float* b_ih  = (const float*)d_in[10];
    const float* W_hh  = (const float*)d_in[11];
    const float* b_hh  = (const float*)d_in[12];
    const float* W_prh = (const float*)d_in[13];
    const float* b_prh = (const float*)d_in[14];
    const float* W_prs = (const float*)d_in[15];
    const float* b_prs = (const float*)d_in[16];
    const float* W_poh = (const float*)d_in[17];
    const float* b_poh = (const float*)d_in[18];
    const float* W_pos = (const float*)d_in[19];
    const float* b_pos = (const float*)d_in[20];
    float* out = (float*)d_out;

    // ---- workspace carve (deterministic every call) ----
    char* wsp = (char*)d_ws;
    size_t off = 0;
    auto alloc = [&](size_t bytes) -> void* {
        void* p = wsp + off;
        off = (off + bytes + 255) & ~(size_t)255;
        return p;
    };
    typedef __hip_bfloat16 bf;
    bf* Wsa_b  = (bf*)alloc((size_t)BELIEF * (STATE + ACTION) * 2);
    bf* Wih_b  = (bf*)alloc((size_t)3 * BELIEF * BELIEF * 2);
    bf* Whh_b  = (bf*)alloc((size_t)3 * BELIEF * BELIEF * 2);
    bf* Wprh_b = (bf*)alloc((size_t)HIDDEN * BELIEF * 2);
    bf* Wprs_b = (bf*)alloc((size_t)2 * STATE * HIDDEN * 2);
    bf* Wpoh_b = (bf*)alloc((size_t)HIDDEN * (BELIEF + EMBED) * 2);
    bf* Wpos_b = (bf*)alloc((size_t)2 * STATE * HIDDEN * 2);
    bf* act_b  = (bf*)alloc((size_t)T * B * ACTION * 2);
    bf* obs_b  = (bf*)alloc((size_t)T * B * EMBED * 2);
    bf* s_b    = (bf*)alloc((size_t)B * STATE * 2);
    bf* x_b    = (bf*)alloc((size_t)B * BELIEF * 2);
    bf* h_b    = (bf*)alloc((size_t)B * BELIEF * 2);
    bf* hq_b   = (bf*)alloc((size_t)B * HIDDEN * 2);
    bf* hs_b   = (bf*)alloc((size_t)T * B * BELIEF * 2);
    bf* hp_b   = (bf*)alloc((size_t)T * B * HIDDEN * 2);
    float* gi_ws = (float*)alloc((size_t)B * 3 * BELIEF * 4);
    float* gh_ws = (float*)alloc((size_t)B * 3 * BELIEF * 4);
    float* mqsq  = (float*)alloc((size_t)B * 2 * STATE * 4);
    float* mpsp  = (float*)alloc((size_t)T * B * 2 * STATE * 4);
    (void)ws_size; (void)in_sizes; (void)n_in; (void)out_size;

    // ---- output layout (tuple return order) ----
    const size_t BEL = (size_t)T * B * BELIEF;
    const size_t SML = (size_t)T * B * STATE;
    float* o_bel  = out;
    float* o_prs  = out + BEL;
    float* o_prm  = o_prs + SML;
    float* o_prsd = o_prm + SML;
    float* o_pos  = o_prsd + SML;
    float* o_pom  = o_pos + SML;
    float* o_posd = o_pom + SML;

    // ---- one-time conversions ----
    ConvP cp;
    cp.src[0] = W_sa;   cp.dst[0] = Wsa_b;  cp.n4[0] = BELIEF * (STATE + ACTION) / 4;
    cp.src[1] = W_ih;   cp.dst[1] = Wih_b;  cp.n4[1] = 3 * BELIEF * BELIEF / 4;
    cp.src[2] = W_hh;   cp.dst[2] = Whh_b;  cp.n4[2] = 3 * BELIEF * BELIEF / 4;
    cp.src[3] = W_prh;  cp.dst[3] = Wprh_b; cp.n4[3] = HIDDEN * BELIEF / 4;
    cp.src[4] = W_prs;  cp.dst[4] = Wprs_b; cp.n4[4] = 2 * STATE * HIDDEN / 4;
    cp.src[5] = W_poh;  cp.dst[5] = Wpoh_b; cp.n4[5] = HIDDEN * (BELIEF + EMBED) / 4;
    cp.src[6] = W_pos;  cp.dst[6] = Wpos_b; cp.n4[6] = 2 * STATE * HIDDEN / 4;
    cp.src[7] = actions; cp.dst[7] = act_b; cp.n4[7] = T * B * ACTION / 4;
    cp.src[8] = observ;  cp.dst[8] = obs_b; cp.n4[8] = T * B * EMBED / 4;
    conv_k<<<2048, BDIM, 0, stream>>>(cp);
    init_k<<<(B * BELIEF) / BDIM, BDIM, 0, stream>>>(prev_state, nonterm, prev_belief, s_b, h_b);

    // ---- sequential scan ----
    for (int t = 0; t < T; t++) {
        {   // x = elu([s|a] @ Wsa^T + b_sa)   [256,1024], K=128+32
            GemmP p{s_b, act_b + (size_t)t * B * ACTION, Wsa_b, b_sa, nullptr, x_b};
            gemm_k<64, 32, 1, true><<<dim3(B / 64, BELIEF / 32, 1), BDIM, 0, stream>>>(
                p, p, STATE, ACTION, B, BELIEF);
        }
        {   // gi = x @ Wih^T + b_ih ; gh = belief @ Whh^T + b_hh   [256,3072] each
            GemmP pg{x_b, nullptr, Wih_b, b_ih, gi_ws, nullptr};
            GemmP ph{h_b, nullptr, Whh_b, b_hh, gh_ws, nullptr};
            gemm_k<128, 64, 0, false><<<dim3(B / 128, 3 * BELIEF / 64, 2), BDIM, 0, stream>>>(
                pg, ph, BELIEF, 0, B, 3 * BELIEF);
        }
        // GRU pointwise -> h (beliefs[t] fp32, h_b bf16, hs_b[t] bf16)
        const float* belf = (t == 0) ? prev_belief : (o_bel + (size_t)(t - 1) * B * BELIEF);
        gru_pw<<<(B * BELIEF) / BDIM, BDIM, 0, stream>>>(
            gi_ws, gh_ws, belf, o_bel + (size_t)t * B * BELIEF, h_b, hs_b + (size_t)t * B * BELIEF);
        {   // hq = elu([h|obs_t] @ Wpoh^T + b_poh)   [256,1024], K=1024+1024
            GemmP p{h_b, obs_b + (size_t)t * B * EMBED, Wpoh_b, b_poh, nullptr, hq_b};
            gemm_k<64, 32, 1, true><<<dim3(B / 64, HIDDEN / 32, 1), BDIM, 0, stream>>>(
                p, p, BELIEF, EMBED, B, HIDDEN);
        }
        {   // [mq|sq_raw] = hq @ Wpos^T + b_pos   [256,256]
            GemmP p{hq_b, nullptr, Wpos_b, b_pos, mqsq, nullptr};
            gemm_k<64, 32, 0, false><<<dim3(B / 64, 2 * STATE / 32, 1), BDIM, 0, stream>>>(
                p, p, HIDDEN, 0, B, 2 * STATE);
        }
        // posterior outputs at t + next-step s_b = bf16(post_s * nt[t+1])
        const float* ntn = (t + 1 < T) ? (nonterm + (size_t)(t + 1) * B) : nullptr;
        head_pw<<<(B * STATE) / BDIM, BDIM, 0, stream>>>(
            mqsq, eps_q + (size_t)t * B * STATE,
            o_pos + (size_t)t * B * STATE, o_pom + (size_t)t * B * STATE,
            o_posd + (size_t)t * B * STATE, B * STATE, ntn, s_b);
    }

    // ---- prior head, batched over all T (does not feed the recurrence) ----
    {   // hp = elu(h @ Wprh^T + b_prh)   [12800,1024]
        GemmP p{hs_b, nullptr, Wprh_b, b_prh, nullptr, hp_b};
        gemm_k<128, 64, 1, true><<<dim3(T * B / 128, HIDDEN / 64, 1), BDIM, 0, stream>>>(
            p, p, BELIEF, 0, T * B, HIDDEN);
    }
    {   // [mp|sp_raw] = hp @ Wprs^T + b_prs   [12800,256]
        GemmP p{hp_b, nullptr, Wprs_b, b_prs, mpsp, nullptr};
        gemm_k<128, 64, 0, false><<<dim3(T * B / 128, 2 * STATE / 64, 1), BDIM, 0, stream>>>(
            p, p, HIDDEN, 0, T * B, 2 * STATE);
    }
    head_pw<<<(T * B * STATE) / BDIM, BDIM, 0, stream>>>(
        mpsp, eps_p, o_prs, o_prm, o_prsd, T * B * STATE, nullptr, nullptr);
}